// Round 1
// baseline (77.654 us; speedup 1.0000x reference)
//
#include <hip/hip_runtime.h>
#include <hip/hip_bf16.h>
#include <math.h>

#define T_LEN   2400
#define NTAPS   16
#define FRAME   160
#define NFRAMES 15
#define SCALE_C    (255.0f / 32768.0f)
#define SCALE_1_C  (32768.0f / 255.0f)

// u2l: s * (32768/255) * (exp(|u|/128 * ln256) - 1) == s * SCALE_1 * (2^(|u|/16) - 1)
__device__ __forceinline__ float u2l_f(float uv) {
    float u = uv - 128.0f;
    float a = fabsf(u);
    float m = SCALE_1_C * (exp2f(a * 0.0625f) - 1.0f);
    return copysignf(m, u);
}

// l2u: clip(128 + s * 128*log1p(SCALE*|x|)/ln256, 0, 255) == clip(128 + s*16*log2(1+SCALE*|x|))
__device__ __forceinline__ float l2u_f(float x) {
    float a = fabsf(x);
    float u = 16.0f * log2f(fmaf(SCALE_C, a, 1.0f));
    u = copysignf(u, x);
    float r = 128.0f + u;
    return fminf(fmaxf(r, 0.0f), 255.0f);
}

__global__ __launch_bounds__(256) void diff_pred_kernel(
        const float* __restrict__ sig,
        const float* __restrict__ lpc,
        float* __restrict__ out) {
    __shared__ float xt_s[NTAPS + T_LEN];   // 2416 floats: 16-zero pad + decoded signal
    __shared__ float lpc_s[NFRAMES * NTAPS]; // 240 floats

    const int b   = blockIdx.x;
    const int tid = threadIdx.x;

    const float* sig_b = sig + (size_t)b * T_LEN;
    const float* lpc_b = lpc + (size_t)b * (NFRAMES * NTAPS);

    if (tid < NTAPS) xt_s[tid] = 0.0f;
    if (tid < NFRAMES * NTAPS) lpc_s[tid] = lpc_b[tid];

    // Stage + decode signal: 600 float4 loads across 256 threads
    const float4* sig4 = (const float4*)sig_b;
    for (int i = tid; i < T_LEN / 4; i += 256) {
        float4 v = sig4[i];
        float4 d;
        d.x = u2l_f(v.x);
        d.y = u2l_f(v.y);
        d.z = u2l_f(v.z);
        d.w = u2l_f(v.w);
        *(float4*)&xt_s[NTAPS + 4 * i] = d;
    }
    __syncthreads();

    float4* out4 = (float4*)(out + (size_t)b * T_LEN);
    for (int i = tid; i < T_LEN / 4; i += 256) {
        const int t0 = 4 * i;
        const int f  = i / 40;            // == t0 / FRAME (4 divides 160, so frame is uniform over the 4)
        const float* lp = &lpc_s[f * NTAPS];

        float acc0 = 0.0f, acc1 = 0.0f, acc2 = 0.0f, acc3 = 0.0f;
        #pragma unroll
        for (int j = 0; j < NTAPS; ++j) {
            const float c = lp[j];
            const int base = NTAPS + t0 - j;
            acc0 = fmaf(c, xt_s[base + 0], acc0);
            acc1 = fmaf(c, xt_s[base + 1], acc1);
            acc2 = fmaf(c, xt_s[base + 2], acc2);
            acc3 = fmaf(c, xt_s[base + 3], acc3);
        }
        float4 o;
        o.x = l2u_f(-acc0);
        o.y = l2u_f(-acc1);
        o.z = l2u_f(-acc2);
        o.w = l2u_f(-acc3);
        out4[i] = o;
    }
}

extern "C" void kernel_launch(void* const* d_in, const int* in_sizes, int n_in,
                              void* d_out, int out_size, void* d_ws, size_t ws_size,
                              hipStream_t stream) {
    const float* sig = (const float*)d_in[0];   // (2048, 2400, 1) f32
    const float* lpc = (const float*)d_in[1];   // (2048, 15, 16) f32
    float* out = (float*)d_out;                  // (2048, 2400, 1) f32

    const int batch = in_sizes[0] / T_LEN;       // 2048
    diff_pred_kernel<<<batch, 256, 0, stream>>>(sig, lpc, out);
}

// Round 2
// 77.640 us; speedup vs baseline: 1.0002x; 1.0002x over previous
//
#include <hip/hip_runtime.h>
#include <hip/hip_bf16.h>
#include <math.h>

#define T_LEN   2400
#define NTAPS   16
#define FRAME   160
#define NFRAMES 15
#define NGROUPS (T_LEN / 4)      // 600 float4 output groups per row
#define SCALE_C    (255.0f / 32768.0f)
#define SCALE_1_C  (32768.0f / 255.0f)

// u2l: s * (32768/255) * (exp(|u|/128 * ln256) - 1) == s * SCALE_1 * (2^(|u|/16) - 1)
__device__ __forceinline__ float u2l_f(float uv) {
    float u = uv - 128.0f;
    float a = fabsf(u);
    float m = SCALE_1_C * (exp2f(a * 0.0625f) - 1.0f);
    return copysignf(m, u);
}

// l2u: clip(128 + s*16*log2(1 + SCALE*|x|), 0, 255)
__device__ __forceinline__ float l2u_f(float x) {
    float a = fabsf(x);
    float u = 16.0f * log2f(fmaf(SCALE_C, a, 1.0f));
    u = copysignf(u, x);
    float r = 128.0f + u;
    return fminf(fmaxf(r, 0.0f), 255.0f);
}

__global__ __launch_bounds__(256) void diff_pred_kernel(
        const float* __restrict__ sig,
        const float* __restrict__ lpc,
        float* __restrict__ out) {
    // xt_s[t0 + m] == xt[t0 - 16 + m]  (16-zero left pad); 16B-aligned for float4 reads
    __shared__ __align__(16) float xt_s[NTAPS + T_LEN];    // 2416 floats
    __shared__ __align__(16) float lpc_s[NFRAMES * NTAPS]; // 240 floats

    const int b   = blockIdx.x;
    const int tid = threadIdx.x;

    const float* sig_b = sig + (size_t)b * T_LEN;
    const float* lpc_b = lpc + (size_t)b * (NFRAMES * NTAPS);

    if (tid < NTAPS) xt_s[tid] = 0.0f;
    if (tid < NFRAMES * NTAPS) lpc_s[tid] = lpc_b[tid];

    // Stage + decode signal: 600 float4 loads across 256 threads
    const float4* sig4 = (const float4*)sig_b;
    for (int i = tid; i < NGROUPS; i += 256) {
        float4 v = sig4[i];
        float4 d;
        d.x = u2l_f(v.x);
        d.y = u2l_f(v.y);
        d.z = u2l_f(v.z);
        d.w = u2l_f(v.w);
        *(float4*)&xt_s[NTAPS + 4 * i] = d;
    }
    __syncthreads();

    float4* out4 = (float4*)(out + (size_t)b * T_LEN);
    for (int i = tid; i < NGROUPS; i += 256) {
        const int t0 = 4 * i;
        const int f  = i / 40;            // frame index; uniform over the 4 outputs

        // 16 coefficients: 4 x ds_read_b128 (64B-aligned)
        const float4 c0 = *(const float4*)&lpc_s[f * NTAPS + 0];
        const float4 c1 = *(const float4*)&lpc_s[f * NTAPS + 4];
        const float4 c2 = *(const float4*)&lpc_s[f * NTAPS + 8];
        const float4 c3 = *(const float4*)&lpc_s[f * NTAPS + 12];
        float c[NTAPS] = {c0.x, c0.y, c0.z, c0.w, c1.x, c1.y, c1.z, c1.w,
                          c2.x, c2.y, c2.z, c2.w, c3.x, c3.y, c3.z, c3.w};

        // 20-float window xt[t0-16 .. t0+3]: 5 x ds_read_b128 (16B-aligned)
        const float4 w0 = *(const float4*)&xt_s[t0 + 0];
        const float4 w1 = *(const float4*)&xt_s[t0 + 4];
        const float4 w2 = *(const float4*)&xt_s[t0 + 8];
        const float4 w3 = *(const float4*)&xt_s[t0 + 12];
        const float4 w4 = *(const float4*)&xt_s[t0 + 16];
        float w[20] = {w0.x, w0.y, w0.z, w0.w, w1.x, w1.y, w1.z, w1.w,
                       w2.x, w2.y, w2.z, w2.w, w3.x, w3.y, w3.z, w3.w,
                       w4.x, w4.y, w4.z, w4.w};

        // out[t0+k] uses xt[t0+k-j] = w[16+k-j]
        float acc[4] = {0.0f, 0.0f, 0.0f, 0.0f};
        #pragma unroll
        for (int j = 0; j < NTAPS; ++j) {
            #pragma unroll
            for (int k = 0; k < 4; ++k) {
                acc[k] = fmaf(c[j], w[16 + k - j], acc[k]);
            }
        }

        float4 o;
        o.x = l2u_f(-acc[0]);
        o.y = l2u_f(-acc[1]);
        o.z = l2u_f(-acc[2]);
        o.w = l2u_f(-acc[3]);
        out4[i] = o;
    }
}

extern "C" void kernel_launch(void* const* d_in, const int* in_sizes, int n_in,
                              void* d_out, int out_size, void* d_ws, size_t ws_size,
                              hipStream_t stream) {
    const float* sig = (const float*)d_in[0];   // (2048, 2400, 1) f32
    const float* lpc = (const float*)d_in[1];   // (2048, 15, 16) f32
    float* out = (float*)d_out;                  // (2048, 2400, 1) f32

    const int batch = in_sizes[0] / T_LEN;       // 2048
    diff_pred_kernel<<<batch, 256, 0, stream>>>(sig, lpc, out);
}